// Round 1
// baseline (553.189 us; speedup 1.0000x reference)
//
#include <hip/hip_runtime.h>
#include <hip/hip_bf16.h>

// CentroidsFlowAD: out[row] = sqrt(max(||e||^2 + min_col(||c||^2 - 2 e.c), 0))
// rows = 32*3136 = 100352, cols = 2048 centroids, K = 1024.
//
// Fast path (needs ~204 MiB ws):
//   1. rowsq_bf16 on centroids  -> cbf (bf16) + csq
//   2. rowsq_bf16 on embeds     -> ebf (bf16) + esq
//   3. gemm_min256: 392 x 8 blocks, 256x256 tile, 8 waves (2x4, 128x64 each),
//      double-buffered LDS (128 KiB), counted vmcnt(8) pipeline, XOR swizzle,
//      setprio around compute. Partial min per 256-col tile -> pmin (8 wide).
//   4. final_min8: 8-way min + sqrt
// Fallback: round-1 fused kernel (proven).

typedef __bf16 bf16x8 __attribute__((ext_vector_type(8)));
typedef __bf16 bf16x4 __attribute__((ext_vector_type(4)));
typedef float f32x4 __attribute__((ext_vector_type(4)));

#define N_ROWS 100352
#define M_CENT 2048
#define D_K 1024

// fast-path geometry
#define BM 256
#define BN 256
#define BKT 64
#define KT_N (D_K / BKT)  // 16 K-tiles
#define NCT (M_CENT / BN) // 8 col tiles

// fallback geometry (round-1, unchanged)
#define TM 128
#define TN 128
#define BK 64
#define NT_TILES (M_CENT / TN)  // 16
#define KT_STEPS (D_K / BK)     // 16

#define AS1 __attribute__((address_space(1)))
#define AS3 __attribute__((address_space(3)))

#define WAITVM(N) asm volatile("s_waitcnt vmcnt(" #N ")" ::: "memory")

// ---- prep: fp32 [rows][1024] -> bf16 row-major + per-row squared norm ----
__global__ __launch_bounds__(256) void rowsq_bf16(const float* __restrict__ src,
                                                  __bf16* __restrict__ dst,
                                                  float* __restrict__ sq) {
  const int m = blockIdx.x;   // row
  const int t = threadIdx.x;  // 256 threads * 4 floats = 1024
  const float4 v = *reinterpret_cast<const float4*>(src + (size_t)m * D_K + t * 4);
  bf16x4 o = {(__bf16)v.x, (__bf16)v.y, (__bf16)v.z, (__bf16)v.w};
  *reinterpret_cast<bf16x4*>(dst + (size_t)m * D_K + t * 4) = o;
  float ss = v.x * v.x + v.y * v.y + v.z * v.z + v.w * v.w;
  ss += __shfl_xor(ss, 1);
  ss += __shfl_xor(ss, 2);
  ss += __shfl_xor(ss, 4);
  ss += __shfl_xor(ss, 8);
  ss += __shfl_xor(ss, 16);
  ss += __shfl_xor(ss, 32);
  __shared__ float ws4[4];
  const int w = t >> 6, l = t & 63;
  if (l == 0) ws4[w] = ss;
  __syncthreads();
  if (t == 0) sq[m] = ws4[0] + ws4[1] + ws4[2] + ws4[3];
}

// ---- fast path: 256x256 tile GEMM + partial min, pipelined ----
// grid: bid = rp*8 + ct (rp-major: the 8 blocks of one A panel land on the 8
// XCDs round-robin; ct == bid%8 pins each B col-panel (512 KB) to one XCD L2).
// Block: 512 threads, 8 waves in 2x4 grid; wave tile 128x64, 8x4 16x16 frags.
// LDS: 2 buffers x (A[256][64] + B[256][64]) bf16 = 128 KiB, 16B-slot XOR
// swizzle (slot ^ (row&7)), staged by global_load_lds w=16 with inverse-
// swizzled global source. Pipeline: stage(t+1) -> vmcnt(8) -> barrier ->
// compute(t) -> barrier. vmcnt never drains to 0 in the main loop.
__global__ __launch_bounds__(512, 2) void gemm_min256(const __bf16* __restrict__ ebf,
                                                      const __bf16* __restrict__ cbf,
                                                      const float* __restrict__ csq,
                                                      float* __restrict__ pmin) {
  __shared__ __align__(16) char lds[2 * 65536];  // [buf][A:32K | B:32K]

  const int t = threadIdx.x;
  const int w = t >> 6;
  const int l = t & 63;
  const int wr = w >> 2, wc = w & 3;  // 2 x 4 wave grid
  const int g = l >> 4, lr = l & 15;
  const int rp = blockIdx.x >> 3, ct = blockIdx.x & 7;
  const long row0 = (long)rp * BM;
  const int col0 = ct * BN;

  // --- per-thread staging bases ---
  // load i (0..3 per operand): slot s = i*512 + t; row = s>>3, sl = s&7.
  // i advances row by 64 (s += 512), so row&7 and sl are i-invariant:
  // src(i) = src0 + i*64*D_K, dst(i) = dst0 + i*8192.
  const int srow = t >> 3, ssl = t & 7;
  const int sswz = (ssl ^ (srow & 7)) << 3;  // element offset of 16B group
  const __bf16* srcA0 = ebf + (row0 + srow) * (size_t)D_K + sswz;
  const __bf16* srcB0 = cbf + (size_t)(col0 + srow) * D_K + sswz;
  const int dst0 = t * 16;

  f32x4 acc[8][4];
#pragma unroll
  for (int m = 0; m < 8; ++m)
#pragma unroll
    for (int n = 0; n < 4; ++n) acc[m][n] = (f32x4){0.f, 0.f, 0.f, 0.f};

  auto stage = [&](int kt, int buf) {
#pragma unroll
    for (int i = 0; i < 4; ++i) {
      __builtin_amdgcn_global_load_lds(
          (const AS1 unsigned int*)(const void*)(srcA0 + (size_t)i * 64 * D_K + kt * BKT),
          (AS3 unsigned int*)(void*)(lds + buf * 65536 + dst0 + i * 8192), 16, 0, 0);
      __builtin_amdgcn_global_load_lds(
          (const AS1 unsigned int*)(const void*)(srcB0 + (size_t)i * 64 * D_K + kt * BKT),
          (AS3 unsigned int*)(void*)(lds + buf * 65536 + 32768 + dst0 + i * 8192), 16, 0,
          0);
    }
  };

  auto compute = [&](int buf) {
    const char* Ab = lds + buf * 65536;
    const char* Bb = Ab + 32768;
    bf16x8 bfr[4][2];  // B frags live across both m-halves (reuse)
#pragma unroll
    for (int n = 0; n < 4; ++n) {
      const int col = wc * 64 + n * 16 + lr;
#pragma unroll
      for (int ks = 0; ks < 2; ++ks) {
        const int slot = ks * 4 + g;
        bfr[n][ks] = *reinterpret_cast<const bf16x8*>(Bb + col * 128 +
                                                      ((slot ^ (col & 7)) << 4));
      }
    }
#pragma unroll
    for (int mh = 0; mh < 2; ++mh) {
      bf16x8 af[4][2];
#pragma unroll
      for (int m = 0; m < 4; ++m) {
        const int row = wr * 128 + mh * 64 + m * 16 + lr;
#pragma unroll
        for (int ks = 0; ks < 2; ++ks) {
          const int slot = ks * 4 + g;
          af[m][ks] = *reinterpret_cast<const bf16x8*>(Ab + row * 128 +
                                                       ((slot ^ (row & 7)) << 4));
        }
      }
#pragma unroll
      for (int ks = 0; ks < 2; ++ks)
#pragma unroll
        for (int m = 0; m < 4; ++m)
#pragma unroll
          for (int n = 0; n < 4; ++n)
            acc[mh * 4 + m][n] = __builtin_amdgcn_mfma_f32_16x16x32_bf16(
                af[m][ks], bfr[n][ks], acc[mh * 4 + m][n], 0, 0, 0);
    }
  };

  // --- pipelined K loop: 16 tiles, double buffer, depth-1 prefetch ---
  stage(0, 0);
  int cur = 0;
  for (int kt = 0; kt < KT_N - 1; ++kt) {
    stage(kt + 1, cur ^ 1);  // issue next tile's 8 loads (safe: that buffer's
                             // readers finished before previous closing barrier)
    WAITVM(8);               // this tile's 8 loads landed; next 8 stay in flight
    __builtin_amdgcn_s_barrier();
    __builtin_amdgcn_s_setprio(1);
    compute(cur);
    __builtin_amdgcn_s_setprio(0);
    __builtin_amdgcn_s_barrier();  // all reads of buf[cur] done before overwrite
    cur ^= 1;
  }
  WAITVM(0);  // last tile: nothing left in flight to preserve
  __builtin_amdgcn_s_barrier();
  __builtin_amdgcn_s_setprio(1);
  compute(cur);
  __builtin_amdgcn_s_setprio(0);
  __builtin_amdgcn_s_barrier();

  // --- partial min over this block's 256 cols: val = ||c||^2 - 2*dot ---
  float runmin[8][4];
#pragma unroll
  for (int m = 0; m < 8; ++m)
#pragma unroll
    for (int r = 0; r < 4; ++r) runmin[m][r] = 3.0e38f;
#pragma unroll
  for (int n = 0; n < 4; ++n) {
    const float cs = csq[col0 + wc * 64 + n * 16 + lr];
#pragma unroll
    for (int m = 0; m < 8; ++m)
#pragma unroll
      for (int r = 0; r < 4; ++r)
        runmin[m][r] = fminf(runmin[m][r], cs - 2.0f * acc[m][n][r]);
  }
#pragma unroll
  for (int m = 0; m < 8; ++m)
#pragma unroll
    for (int r = 0; r < 4; ++r) {
      float v = runmin[m][r];
      v = fminf(v, __shfl_xor(v, 1));
      v = fminf(v, __shfl_xor(v, 2));
      v = fminf(v, __shfl_xor(v, 4));
      v = fminf(v, __shfl_xor(v, 8));
      runmin[m][r] = v;
    }
  float* rowmin = (float*)(void*)lds;  // alias: [4 wc][256 rows], reads done
  if (lr == 0) {
#pragma unroll
    for (int m = 0; m < 8; ++m)
#pragma unroll
      for (int r = 0; r < 4; ++r)
        rowmin[wc * 256 + wr * 128 + m * 16 + g * 4 + r] = runmin[m][r];
  }
  __syncthreads();
  if (t < BM) {
    const float v = fminf(fminf(rowmin[t], rowmin[256 + t]),
                          fminf(rowmin[512 + t], rowmin[768 + t]));
    pmin[(row0 + t) * NCT + ct] = v;
  }
}

// ---- final: 8-way min + sqrt ----
__global__ __launch_bounds__(256) void final_min8(const float* __restrict__ esq,
                                                  const float* __restrict__ pmin,
                                                  float* __restrict__ out) {
  const int r = blockIdx.x * 256 + threadIdx.x;
  const float4* p = reinterpret_cast<const float4*>(pmin + (size_t)r * 8);
  float4 a = p[0], b = p[1];
  float m = fminf(fminf(fminf(a.x, a.y), fminf(a.z, a.w)),
                  fminf(fminf(b.x, b.y), fminf(b.z, b.w)));
  out[r] = sqrtf(fmaxf(esq[r] + m, 0.f));
}

// =================== round-1 fallback (proven) ===================
template <bool WS>
__global__ __launch_bounds__(256, 2) void fused_min(const float* __restrict__ embeds,
                                                    const float* __restrict__ centf,
                                                    const __bf16* __restrict__ cbf,
                                                    const float* __restrict__ csq,
                                                    float* __restrict__ out) {
  __shared__ __align__(16) char Ab[TM * 128];
  __shared__ __align__(16) char Bb[TN * 128];
  __shared__ float rowmin2[2][TM];
  __shared__ float sqrow[TM];
  __shared__ float colsq[TN];

  const int t = threadIdx.x;
  const int w = t >> 6;
  const int l = t & 63;
  const int wr = w >> 1, wc = w & 1;
  const int g = l >> 4, lr = l & 15;
  const long row0 = (long)blockIdx.x * TM;

  float runmin[4][4];
#pragma unroll
  for (int m = 0; m < 4; ++m)
#pragma unroll
    for (int r = 0; r < 4; ++r) runmin[m][r] = 3.0e38f;

  float sqpart[8];
#pragma unroll
  for (int c = 0; c < 8; ++c) sqpart[c] = 0.f;

  for (int nt = 0; nt < NT_TILES; ++nt) {
    const int col0 = nt * TN;
    f32x4 acc[4][4];
#pragma unroll
    for (int m = 0; m < 4; ++m)
#pragma unroll
      for (int n = 0; n < 4; ++n) acc[m][n] = (f32x4){0.f, 0.f, 0.f, 0.f};

    float cpart[8];
    if constexpr (!WS) {
#pragma unroll
      for (int c = 0; c < 8; ++c) cpart[c] = 0.f;
    }

    for (int kt = 0; kt < KT_STEPS; ++kt) {
      __syncthreads();
      if constexpr (WS) {
#pragma unroll
        for (int i = 0; i < 4; ++i) {
          const int s = (w * 4 + i) * 64 + l;
          const int col = s >> 3, sl = s & 7;
          const __bf16* src =
              cbf + (size_t)(col0 + col) * D_K + kt * BK + ((sl ^ (col & 7)) << 3);
          __builtin_amdgcn_global_load_lds(
              (const AS1 unsigned int*)(const void*)src,
              (AS3 unsigned int*)(void*)(Bb + (w * 4 + i) * 1024), 16, 0, 0);
        }
      } else {
#pragma unroll
        for (int c = 0; c < 8; ++c) {
          const int f = c * 256 + t;
          const int col = f >> 4, kq = f & 15;
          const float4 v = *reinterpret_cast<const float4*>(
              centf + (size_t)(col0 + col) * D_K + kt * BK + kq * 4);
          cpart[c] += v.x * v.x + v.y * v.y + v.z * v.z + v.w * v.w;
          bf16x4 o = {(__bf16)v.x, (__bf16)v.y, (__bf16)v.z, (__bf16)v.w};
          const int slot = kq >> 1;
          *reinterpret_cast<bf16x4*>(Bb + col * 128 + ((slot ^ (col & 7)) << 4) +
                                     (kq & 1) * 8) = o;
        }
      }
#pragma unroll
      for (int c = 0; c < 8; ++c) {
        const int f = c * 256 + t;
        const int row = f >> 4, kq = f & 15;
        const float4 v = *reinterpret_cast<const float4*>(
            embeds + (row0 + row) * (long)D_K + kt * BK + kq * 4);
        if (nt == 0) sqpart[c] += v.x * v.x + v.y * v.y + v.z * v.z + v.w * v.w;
        bf16x4 o = {(__bf16)v.x, (__bf16)v.y, (__bf16)v.z, (__bf16)v.w};
        const int slot = kq >> 1;
        *reinterpret_cast<bf16x4*>(Ab + row * 128 + ((slot ^ (row & 7)) << 4) +
                                   (kq & 1) * 8) = o;
      }
      __syncthreads();
#pragma unroll
      for (int ks = 0; ks < 2; ++ks) {
        bf16x8 af[4], bfr[4];
#pragma unroll
        for (int m = 0; m < 4; ++m) {
          const int row = wr * 64 + m * 16 + lr;
          const int slot = ks * 4 + g;
          af[m] = *reinterpret_cast<const bf16x8*>(Ab + row * 128 +
                                                   ((slot ^ (row & 7)) << 4));
        }
#pragma unroll
        for (int n = 0; n < 4; ++n) {
          const int col = wc * 64 + n * 16 + lr;
          const int slot = ks * 4 + g;
          bfr[n] = *reinterpret_cast<const bf16x8*>(Bb + col * 128 +
                                                    ((slot ^ (col & 7)) << 4));
        }
#pragma unroll
        for (int m = 0; m < 4; ++m)
#pragma unroll
          for (int n = 0; n < 4; ++n)
            acc[m][n] =
                __builtin_amdgcn_mfma_f32_16x16x32_bf16(af[m], bfr[n], acc[m][n], 0, 0, 0);
      }
    }

    if (nt == 0) {
#pragma unroll
      for (int c = 0; c < 8; ++c) {
        float ss = sqpart[c];
        ss += __shfl_xor(ss, 1);
        ss += __shfl_xor(ss, 2);
        ss += __shfl_xor(ss, 4);
        ss += __shfl_xor(ss, 8);
        if (lr == 0) sqrow[c * 16 + (w * 4 + g)] = ss;
      }
    }
    if constexpr (!WS) {
#pragma unroll
      for (int c = 0; c < 8; ++c) {
        float ss = cpart[c];
        ss += __shfl_xor(ss, 1);
        ss += __shfl_xor(ss, 2);
        ss += __shfl_xor(ss, 4);
        ss += __shfl_xor(ss, 8);
        if (lr == 0) colsq[c * 16 + (w * 4 + g)] = ss;
      }
      __syncthreads();
    }

#pragma unroll
    for (int n = 0; n < 4; ++n) {
      float cs;
      if constexpr (WS)
        cs = csq[col0 + wc * 64 + n * 16 + lr];
      else
        cs = colsq[wc * 64 + n * 16 + lr];
#pragma unroll
      for (int m = 0; m < 4; ++m)
#pragma unroll
        for (int r = 0; r < 4; ++r)
          runmin[m][r] = fminf(runmin[m][r], cs - 2.0f * acc[m][n][r]);
    }
  }

#pragma unroll
  for (int m = 0; m < 4; ++m)
#pragma unroll
    for (int r = 0; r < 4; ++r) {
      float v = runmin[m][r];
      v = fminf(v, __shfl_xor(v, 1));
      v = fminf(v, __shfl_xor(v, 2));
      v = fminf(v, __shfl_xor(v, 4));
      v = fminf(v, __shfl_xor(v, 8));
      runmin[m][r] = v;
    }
  if (lr == 0) {
#pragma unroll
    for (int m = 0; m < 4; ++m)
#pragma unroll
      for (int r = 0; r < 4; ++r)
        rowmin2[wc][wr * 64 + m * 16 + g * 4 + r] = runmin[m][r];
  }
  __syncthreads();
  if (t < TM) {
    const float v = fminf(rowmin2[0][t], rowmin2[1][t]);
    out[row0 + t] = sqrtf(fmaxf(sqrow[t] + v, 0.f));
  }
}

extern "C" void kernel_launch(void* const* d_in, const int* in_sizes, int n_in,
                              void* d_out, int out_size, void* d_ws, size_t ws_size,
                              hipStream_t stream) {
  const float* embeds = (const float*)d_in[0];
  const float* cent = (const float*)d_in[1];
  float* out = (float*)d_out;

  // ws layout for the fast path
  const size_t off_cbf = 0;
  const size_t off_csq = off_cbf + (size_t)M_CENT * D_K * 2;        // 4 MiB
  const size_t off_ebf = off_csq + (size_t)M_CENT * 4;              // +8 KiB
  const size_t off_esq = off_ebf + (size_t)N_ROWS * D_K * 2;        // +196 MiB
  const size_t off_pmin = off_esq + (size_t)N_ROWS * 4;             // +392 KiB
  const size_t need_full = off_pmin + (size_t)N_ROWS * NCT * 4;     // +3.1 MiB
  const size_t need_small = (size_t)M_CENT * D_K * 2 + (size_t)M_CENT * 4;

  if (ws_size >= need_full) {
    __bf16* cbf = (__bf16*)((char*)d_ws + off_cbf);
    float* csq = (float*)((char*)d_ws + off_csq);
    __bf16* ebf = (__bf16*)((char*)d_ws + off_ebf);
    float* esq = (float*)((char*)d_ws + off_esq);
    float* pmin = (float*)((char*)d_ws + off_pmin);
    rowsq_bf16<<<M_CENT, 256, 0, stream>>>(cent, cbf, csq);
    rowsq_bf16<<<N_ROWS, 256, 0, stream>>>(embeds, ebf, esq);
    gemm_min256<<<(N_ROWS / BM) * NCT, 512, 0, stream>>>(ebf, cbf, csq, pmin);
    final_min8<<<N_ROWS / 256, 256, 0, stream>>>(esq, pmin, out);
  } else if (ws_size >= need_small) {
    __bf16* cbf = (__bf16*)d_ws;
    float* csq = (float*)((char*)d_ws + (size_t)M_CENT * D_K * 2);
    rowsq_bf16<<<M_CENT, 256, 0, stream>>>(cent, cbf, csq);
    fused_min<true><<<N_ROWS / TM, 256, 0, stream>>>(embeds, cent, cbf, csq, out);
  } else {
    fused_min<false><<<N_ROWS / TM, 256, 0, stream>>>(embeds, cent, nullptr, nullptr, out);
  }
}

// Round 2
// 487.550 us; speedup vs baseline: 1.1346x; 1.1346x over previous
//
#include <hip/hip_runtime.h>
#include <hip/hip_bf16.h>

// CentroidsFlowAD: out[row] = sqrt(max(||e||^2 + min_col(||c||^2 - 2 e.c), 0))
// rows = 32*3136 = 100352, cols = 2048 centroids, K = 1024.
//
// Fast path (needs ~204 MiB ws):
//   1. rowsq_bf16 on centroids  -> cbf (bf16) + csq
//   2. rowsq_bf16 on embeds     -> ebf (bf16) + esq
//   3. gemm_min256: 256x256 tile, 8 waves, 4-phase-per-K-tile interleaved
//      schedule (T3+T4): each phase = ds_read quadrant frags | stage one
//      16KB half-tile | counted vmcnt (never 0) | raw s_barrier | setprio+
//      16 MFMA. Interleaved wave mapping so quadrant (mh,nh) reads only
//      half (mh) of A / (nh) of B -> provable 3-phase flight per unit.
//      XCD swizzle: each XCD owns contiguous rp ranges x all 8 ct.
//   4. final_min8: 8-way min + sqrt
// Fallback: round-1 fused kernel (proven).

typedef __bf16 bf16x8 __attribute__((ext_vector_type(8)));
typedef __bf16 bf16x4 __attribute__((ext_vector_type(4)));
typedef float f32x4 __attribute__((ext_vector_type(4)));

#define N_ROWS 100352
#define M_CENT 2048
#define D_K 1024

// fast-path geometry
#define BM 256
#define BN 256
#define BKT 64
#define KT_N (D_K / BKT)   // 16 K-tiles
#define NCT (M_CENT / BN)  // 8 col tiles
#define NBLK ((N_ROWS / BM) * NCT)  // 3136
#define BPX (NBLK / 8)              // 392 blocks per XCD

// fallback geometry (round-1, unchanged)
#define TM 128
#define TN 128
#define BK 64
#define NT_TILES (M_CENT / TN)  // 16
#define KT_STEPS (D_K / BK)     // 16

#define AS1 __attribute__((address_space(1)))
#define AS3 __attribute__((address_space(3)))

#define WAITVM(N) asm volatile("s_waitcnt vmcnt(" #N ")" ::: "memory")
#define FENCE asm volatile("" ::: "memory")

// ---- prep: fp32 [rows][1024] -> bf16 row-major + per-row squared norm ----
__global__ __launch_bounds__(256) void rowsq_bf16(const float* __restrict__ src,
                                                  __bf16* __restrict__ dst,
                                                  float* __restrict__ sq) {
  const int m = blockIdx.x;   // row
  const int t = threadIdx.x;  // 256 threads * 4 floats = 1024
  const float4 v = *reinterpret_cast<const float4*>(src + (size_t)m * D_K + t * 4);
  bf16x4 o = {(__bf16)v.x, (__bf16)v.y, (__bf16)v.z, (__bf16)v.w};
  *reinterpret_cast<bf16x4*>(dst + (size_t)m * D_K + t * 4) = o;
  float ss = v.x * v.x + v.y * v.y + v.z * v.z + v.w * v.w;
  ss += __shfl_xor(ss, 1);
  ss += __shfl_xor(ss, 2);
  ss += __shfl_xor(ss, 4);
  ss += __shfl_xor(ss, 8);
  ss += __shfl_xor(ss, 16);
  ss += __shfl_xor(ss, 32);
  __shared__ float ws4[4];
  const int w = t >> 6, l = t & 63;
  if (l == 0) ws4[w] = ss;
  __syncthreads();
  if (t == 0) sq[m] = ws4[0] + ws4[1] + ws4[2] + ws4[3];
}

// ---- fast path: 256x256 tile GEMM + partial min, 4-phase pipelined ----
// Waves: 8 = wr(2) x wc(4). Interleaved wave tile: wave rows =
// {mh*128 + wr*64 + m*16}, m=0..3, mh=quadrant row half; wave cols =
// {nh*128 + wc*32 + n*16}, n=0..1, nh=quadrant col half.
// LDS: buf[2] x (A[256][64] | B[256][64]) bf16 = 128 KiB, 16B-slot XOR
// swizzle (slot ^ (row&7)); stage units (16 KB each): u0=A-half0, u1=B-half0,
// u2=B-half1, u3=A-half1, 2 global_load_lds/thread per unit.
// Per K-tile t (buf=t&1), 4 phases; phase p stages unit p of tile t+1:
//   P0: ds_read af(mh0)+bf0; stage u0; vmcnt(4); bar; mfma(mh0,nh0)
//   P1: ds_read bf1;         stage u1; vmcnt(4); bar; mfma(mh0,nh1)
//   P2: ds_read af(mh1);     stage u2;           bar; mfma(mh1,nh0)
//   P3:                      stage u3; vmcnt(4); bar; mfma(mh1,nh1)
// Each unit has >= 3 phases of flight; vmcnt never drains to 0 mid-loop.
__global__ __launch_bounds__(512, 2) void gemm_min256(const __bf16* __restrict__ ebf,
                                                      const __bf16* __restrict__ cbf,
                                                      const float* __restrict__ csq,
                                                      float* __restrict__ pmin) {
  __shared__ __align__(16) char lds[2 * 65536];  // [buf][A:32K | B:32K]

  const int t = threadIdx.x;
  const int w = t >> 6;
  const int l = t & 63;
  const int wr = w >> 2, wc = w & 3;  // 2 x 4 wave grid
  const int g = l >> 4, lr = l & 15;

  // XCD swizzle: physical XCD = bid&7 (round-robin). Give XCD k the swz
  // range [k*392,(k+1)*392) = rp in [49k,49k+49) x all 8 ct -> per-round
  // L2 set ~ 4 A-panels (2MB) + K-synchronized B slices.
  const int b = blockIdx.x;
  const int swz = (b & 7) * BPX + (b >> 3);
  const int rp = swz >> 3, ct = swz & 7;
  const long row0 = (long)rp * BM;
  const int col0 = ct * BN;

  // staging bases: thread t covers 16B group; load i of a half advances
  // rows by 64 (row&7 invariant -> swizzle i-invariant).
  const int srow = t >> 3, ssl = t & 7;
  const int sswz = (ssl ^ (srow & 7)) << 3;
  const __bf16* srcA0 = ebf + (row0 + srow) * (size_t)D_K + sswz;
  const __bf16* srcB0 = cbf + (size_t)(col0 + srow) * D_K + sswz;
  const int dst0 = t * 16;

  f32x4 acc[2][4][2][2];  // [mh][m][nh][n]
#pragma unroll
  for (int mh = 0; mh < 2; ++mh)
#pragma unroll
    for (int m = 0; m < 4; ++m)
#pragma unroll
      for (int nh = 0; nh < 2; ++nh)
#pragma unroll
        for (int n = 0; n < 2; ++n) acc[mh][m][nh][n] = (f32x4){0.f, 0.f, 0.f, 0.f};

  bf16x8 af[4][2];   // current mh's A frags
  bf16x8 bf0[2][2];  // nh=0 B frags
  bf16x8 bf1[2][2];  // nh=1 B frags

  // u: 0=A-half0, 1=B-half0, 2=B-half1, 3=A-half1 (deadline order)
  auto stage_unit = [&](int kt, int buf, int u) {
    const bool isA = (u == 0) | (u == 3);
    const int ih = (u == 0 || u == 1) ? 0 : 1;
    const __bf16* s0 = (isA ? srcA0 : srcB0) + (size_t)(ih * 128) * D_K + kt * BKT;
    char* d0 = lds + buf * 65536 + (isA ? 0 : 32768) + ih * 16384 + dst0;
#pragma unroll
    for (int i = 0; i < 2; ++i)
      __builtin_amdgcn_global_load_lds((const AS1 unsigned int*)(const void*)(s0 + (size_t)i * 64 * D_K),
                                       (AS3 unsigned int*)(void*)(d0 + i * 8192), 16, 0, 0);
  };

  auto read_af = [&](int buf, int mh) {
#pragma unroll
    for (int m = 0; m < 4; ++m) {
      const int row = mh * 128 + wr * 64 + m * 16 + lr;
#pragma unroll
      for (int ks = 0; ks < 2; ++ks) {
        const int slot = ks * 4 + g;
        af[m][ks] = *reinterpret_cast<const bf16x8*>(lds + buf * 65536 + row * 128 +
                                                     ((slot ^ (row & 7)) << 4));
      }
    }
  };
  auto read_bf = [&](int buf, int nh, bf16x8(&bf)[2][2]) {
#pragma unroll
    for (int n = 0; n < 2; ++n) {
      const int col = nh * 128 + wc * 32 + n * 16 + lr;
#pragma unroll
      for (int ks = 0; ks < 2; ++ks) {
        const int slot = ks * 4 + g;
        bf[n][ks] = *reinterpret_cast<const bf16x8*>(lds + buf * 65536 + 32768 +
                                                     col * 128 + ((slot ^ (col & 7)) << 4));
      }
    }
  };
  auto mfma16 = [&](int mh, int nh, bf16x8(&bf)[2][2]) {
    __builtin_amdgcn_s_setprio(1);
#pragma unroll
    for (int ks = 0; ks < 2; ++ks)
#pragma unroll
      for (int m = 0; m < 4; ++m)
#pragma unroll
        for (int n = 0; n < 2; ++n)
          acc[mh][m][nh][n] = __builtin_amdgcn_mfma_f32_16x16x32_bf16(
              af[m][ks], bf[n][ks], acc[mh][m][nh][n], 0, 0, 0);
    __builtin_amdgcn_s_setprio(0);
  };

  // prologue: tile 0 fully staged, drain once (allowed outside main loop)
  stage_unit(0, 0, 0);
  stage_unit(0, 0, 1);
  stage_unit(0, 0, 2);
  stage_unit(0, 0, 3);
  WAITVM(0);
  __builtin_amdgcn_s_barrier();
  FENCE;

  // interior tiles: stage tile kt+1 during kt's phases
  for (int kt = 0; kt < KT_N - 1; ++kt) {
    const int buf = kt & 1, nbuf = buf ^ 1;
    // P0
    read_af(buf, 0);
    read_bf(buf, 0, bf0);
    stage_unit(kt + 1, nbuf, 0);
    WAITVM(4);
    __builtin_amdgcn_s_barrier();
    FENCE;
    mfma16(0, 0, bf0);
    // P1
    read_bf(buf, 1, bf1);
    stage_unit(kt + 1, nbuf, 1);
    WAITVM(4);
    __builtin_amdgcn_s_barrier();
    FENCE;
    mfma16(0, 1, bf1);
    // P2
    read_af(buf, 1);
    stage_unit(kt + 1, nbuf, 2);
    FENCE;
    __builtin_amdgcn_s_barrier();
    FENCE;
    mfma16(1, 0, bf0);
    // P3
    stage_unit(kt + 1, nbuf, 3);
    WAITVM(4);
    __builtin_amdgcn_s_barrier();
    FENCE;
    mfma16(1, 1, bf1);
  }
  // tail tile (kt = 15, buf = 1): no staging; finish draining counted
  {
    const int buf = (KT_N - 1) & 1;
    read_af(buf, 0);
    read_bf(buf, 0, bf0);
    WAITVM(2);  // forces u2 (B-half1) landed; u3 still in flight
    __builtin_amdgcn_s_barrier();
    FENCE;
    mfma16(0, 0, bf0);
    read_bf(buf, 1, bf1);
    WAITVM(0);  // forces u3 (A-half1) landed
    __builtin_amdgcn_s_barrier();
    FENCE;
    mfma16(0, 1, bf1);
    read_af(buf, 1);
    FENCE;
    __builtin_amdgcn_s_barrier();
    FENCE;
    mfma16(1, 0, bf0);
    mfma16(1, 1, bf1);
  }

  // --- partial min over this block's 256 cols: val = ||c||^2 - 2*dot ---
  float runmin[2][4][4];  // [mh][m][r]
#pragma unroll
  for (int mh = 0; mh < 2; ++mh)
#pragma unroll
    for (int m = 0; m < 4; ++m)
#pragma unroll
      for (int r = 0; r < 4; ++r) runmin[mh][m][r] = 3.0e38f;
#pragma unroll
  for (int nh = 0; nh < 2; ++nh)
#pragma unroll
    for (int n = 0; n < 2; ++n) {
      const float cs = csq[col0 + nh * 128 + wc * 32 + n * 16 + lr];
#pragma unroll
      for (int mh = 0; mh < 2; ++mh)
#pragma unroll
        for (int m = 0; m < 4; ++m)
#pragma unroll
          for (int r = 0; r < 4; ++r)
            runmin[mh][m][r] = fminf(runmin[mh][m][r], cs - 2.0f * acc[mh][m][nh][n][r]);
    }
#pragma unroll
  for (int mh = 0; mh < 2; ++mh)
#pragma unroll
    for (int m = 0; m < 4; ++m)
#pragma unroll
      for (int r = 0; r < 4; ++r) {
        float v = runmin[mh][m][r];
        v = fminf(v, __shfl_xor(v, 1));
        v = fminf(v, __shfl_xor(v, 2));
        v = fminf(v, __shfl_xor(v, 4));
        v = fminf(v, __shfl_xor(v, 8));
        runmin[mh][m][r] = v;
      }
  float* rowmin = (float*)(void*)lds;  // alias: [4 wc][256 rows]
  __syncthreads();
  if (lr == 0) {
#pragma unroll
    for (int mh = 0; mh < 2; ++mh)
#pragma unroll
      for (int m = 0; m < 4; ++m)
#pragma unroll
        for (int r = 0; r < 4; ++r)
          rowmin[wc * 256 + mh * 128 + wr * 64 + m * 16 + g * 4 + r] = runmin[mh][m][r];
  }
  __syncthreads();
  if (t < BM) {
    const float v = fminf(fminf(rowmin[t], rowmin[256 + t]),
                          fminf(rowmin[512 + t], rowmin[768 + t]));
    pmin[(row0 + t) * NCT + ct] = v;
  }
}

// ---- final: 8-way min + sqrt ----
__global__ __launch_bounds__(256) void final_min8(const float* __restrict__ esq,
                                                  const float* __restrict__ pmin,
                                                  float* __restrict__ out) {
  const int r = blockIdx.x * 256 + threadIdx.x;
  const float4* p = reinterpret_cast<const float4*>(pmin + (size_t)r * 8);
  float4 a = p[0], b = p[1];
  float m = fminf(fminf(fminf(a.x, a.y), fminf(a.z, a.w)),
                  fminf(fminf(b.x, b.y), fminf(b.z, b.w)));
  out[r] = sqrtf(fmaxf(esq[r] + m, 0.f));
}

// =================== round-1 fallback (proven) ===================
template <bool WS>
__global__ __launch_bounds__(256, 2) void fused_min(const float* __restrict__ embeds,
                                                    const float* __restrict__ centf,
                                                    const __bf16* __restrict__ cbf,
                                                    const float* __restrict__ csq,
                                                    float* __restrict__ out) {
  __shared__ __align__(16) char Ab[TM * 128];
  __shared__ __align__(16) char Bb[TN * 128];
  __shared__ float rowmin2[2][TM];
  __shared__ float sqrow[TM];
  __shared__ float colsq[TN];

  const int t = threadIdx.x;
  const int w = t >> 6;
  const int l = t & 63;
  const int wr = w >> 1, wc = w & 1;
  const int g = l >> 4, lr = l & 15;
  const long row0 = (long)blockIdx.x * TM;

  float runmin[4][4];
#pragma unroll
  for (int m = 0; m < 4; ++m)
#pragma unroll
    for (int r = 0; r < 4; ++r) runmin[m][r] = 3.0e38f;

  float sqpart[8];
#pragma unroll
  for (int c = 0; c < 8; ++c) sqpart[c] = 0.f;

  for (int nt = 0; nt < NT_TILES; ++nt) {
    const int col0 = nt * TN;
    f32x4 acc[4][4];
#pragma unroll
    for (int m = 0; m < 4; ++m)
#pragma unroll
      for (int n = 0; n < 4; ++n) acc[m][n] = (f32x4){0.f, 0.f, 0.f, 0.f};

    float cpart[8];
    if constexpr (!WS) {
#pragma unroll
      for (int c = 0; c < 8; ++c) cpart[c] = 0.f;
    }

    for (int kt = 0; kt < KT_STEPS; ++kt) {
      __syncthreads();
      if constexpr (WS) {
#pragma unroll
        for (int i = 0; i < 4; ++i) {
          const int s = (w * 4 + i) * 64 + l;
          const int col = s >> 3, sl = s & 7;
          const __bf16* src =
              cbf + (size_t)(col0 + col) * D_K + kt * BK + ((sl ^ (col & 7)) << 3);
          __builtin_amdgcn_global_load_lds(
              (const AS1 unsigned int*)(const void*)src,
              (AS3 unsigned int*)(void*)(Bb + (w * 4 + i) * 1024), 16, 0, 0);
        }
      } else {
#pragma unroll
        for (int c = 0; c < 8; ++c) {
          const int f = c * 256 + t;
          const int col = f >> 4, kq = f & 15;
          const float4 v = *reinterpret_cast<const float4*>(
              centf + (size_t)(col0 + col) * D_K + kt * BK + kq * 4);
          cpart[c] += v.x * v.x + v.y * v.y + v.z * v.z + v.w * v.w;
          bf16x4 o = {(__bf16)v.x, (__bf16)v.y, (__bf16)v.z, (__bf16)v.w};
          const int slot = kq >> 1;
          *reinterpret_cast<bf16x4*>(Bb + col * 128 + ((slot ^ (col & 7)) << 4) +
                                     (kq & 1) * 8) = o;
        }
      }
#pragma unroll
      for (int c = 0; c < 8; ++c) {
        const int f = c * 256 + t;
        const int row = f >> 4, kq = f & 15;
        const float4 v = *reinterpret_cast<const float4*>(
            embeds + (row0 + row) * (long)D_K + kt * BK + kq * 4);
        if (nt == 0) sqpart[c] += v.x * v.x + v.y * v.y + v.z * v.z + v.w * v.w;
        bf16x4 o = {(__bf16)v.x, (__bf16)v.y, (__bf16)v.z, (__bf16)v.w};
        const int slot = kq >> 1;
        *reinterpret_cast<bf16x4*>(Ab + row * 128 + ((slot ^ (row & 7)) << 4) +
                                   (kq & 1) * 8) = o;
      }
      __syncthreads();
#pragma unroll
      for (int ks = 0; ks < 2; ++ks) {
        bf16x8 af[4], bfr[4];
#pragma unroll
        for (int m = 0; m < 4; ++m) {
          const int row = wr * 64 + m * 16 + lr;
          const int slot = ks * 4 + g;
          af[m] = *reinterpret_cast<const bf16x8*>(Ab + row * 128 +
                                                   ((slot ^ (row & 7)) << 4));
        }
#pragma unroll
        for (int n = 0; n < 4; ++n) {
          const int col = wc * 64 + n * 16 + lr;
          const int slot = ks * 4 + g;
          bfr[n] = *reinterpret_cast<const bf16x8*>(Bb + col * 128 +
                                                    ((slot ^ (col & 7)) << 4));
        }
#pragma unroll
        for (int m = 0; m < 4; ++m)
#pragma unroll
          for (int n = 0; n < 4; ++n)
            acc[m][n] =
                __builtin_amdgcn_mfma_f32_16x16x32_bf16(af[m], bfr[n], acc[m][n], 0, 0, 0);
      }
    }

    if (nt == 0) {
#pragma unroll
      for (int c = 0; c < 8; ++c) {
        float ss = sqpart[c];
        ss += __shfl_xor(ss, 1);
        ss += __shfl_xor(ss, 2);
        ss += __shfl_xor(ss, 4);
        ss += __shfl_xor(ss, 8);
        if (lr == 0) sqrow[c * 16 + (w * 4 + g)] = ss;
      }
    }
    if constexpr (!WS) {
#pragma unroll
      for (int c = 0; c < 8; ++c) {
        float ss = cpart[c];
        ss += __shfl_xor(ss, 1);
        ss += __shfl_xor(ss, 2);
        ss += __shfl_xor(ss, 4);
        ss += __shfl_xor(ss, 8);
        if (lr == 0) colsq[c * 16 + (w * 4 + g)] = ss;
      }
      __syncthreads();
    }

#pragma unroll
    for (int n = 0; n < 4; ++n) {
      float cs;
      if constexpr (WS)
        cs = csq[col0 + wc * 64 + n * 16 + lr];
      else
        cs = colsq[wc * 64 + n * 16 + lr];
#pragma unroll
      for (int m = 0; m < 4; ++m)
#pragma unroll
        for (int r = 0; r < 4; ++r)
          runmin[m][r] = fminf(runmin[m][r], cs - 2.0f * acc[m][n][r]);
    }
  }

#pragma unroll
  for (int m = 0; m < 4; ++m)
#pragma unroll
    for (int r = 0; r < 4; ++r) {
      float v = runmin[m][r];
      v = fminf(v, __shfl_xor(v, 1));
      v = fminf(v, __shfl_xor(v, 2));
      v = fminf(v, __shfl_xor(v, 4));
      v = fminf(v, __shfl_xor(v, 8));
      runmin[m][r] = v;
    }
  if (lr == 0) {
#pragma unroll
    for (int m = 0; m < 4; ++m)
#pragma unroll
      for (int r = 0; r < 4; ++r)
        rowmin2[wc][wr * 64 + m * 16 + g * 4 + r] = runmin[m][r];
  }
  __syncthreads();
  if (t < TM) {
    const float v = fminf(rowmin2[0][t], rowmin2[1][t]);
    out[row0 + t] = sqrtf(fmaxf(sqrow[t] + v, 0.f));
  }
}

extern "C" void kernel_launch(void* const* d_in, const int* in_sizes, int n_in,
                              void* d_out, int out_size, void* d_ws, size_t ws_size,
                              hipStream_t stream) {
  const float* embeds = (const float*)d_in[0];
  const float* cent = (const float*)d_in[1];
  float* out = (float*)d_out;

  // ws layout for the fast path
  const size_t off_cbf = 0;
  const size_t off_csq = off_cbf + (size_t)M_CENT * D_K * 2;        // 4 MiB
  const size_t off_ebf = off_csq + (size_t)M_CENT * 4;              // +8 KiB
  const size_t off_esq = off_ebf + (size_t)N_ROWS * D_K * 2;        // +196 MiB
  const size_t off_pmin = off_esq + (size_t)N_ROWS * 4;             // +392 KiB
  const size_t need_full = off_pmin + (size_t)N_ROWS * NCT * 4;     // +3.1 MiB
  const size_t need_small = (size_t)M_CENT * D_K * 2 + (size_t)M_CENT * 4;

  if (ws_size >= need_full) {
    __bf16* cbf = (__bf16*)((char*)d_ws + off_cbf);
    float* csq = (float*)((char*)d_ws + off_csq);
    __bf16* ebf = (__bf16*)((char*)d_ws + off_ebf);
    float* esq = (float*)((char*)d_ws + off_esq);
    float* pmin = (float*)((char*)d_ws + off_pmin);
    rowsq_bf16<<<M_CENT, 256, 0, stream>>>(cent, cbf, csq);
    rowsq_bf16<<<N_ROWS, 256, 0, stream>>>(embeds, ebf, esq);
    gemm_min256<<<NBLK, 512, 0, stream>>>(ebf, cbf, csq, pmin);
    final_min8<<<N_ROWS / 256, 256, 0, stream>>>(esq, pmin, out);
  } else if (ws_size >= need_small) {
    __bf16* cbf = (__bf16*)d_ws;
    float* csq = (float*)((char*)d_ws + (size_t)M_CENT * D_K * 2);
    rowsq_bf16<<<M_CENT, 256, 0, stream>>>(cent, cbf, csq);
    fused_min<true><<<N_ROWS / TM, 256, 0, stream>>>(embeds, cent, cbf, csq, out);
  } else {
    fused_min<false><<<N_ROWS / TM, 256, 0, stream>>>(embeds, cent, nullptr, nullptr, out);
  }
}